// Round 13
// baseline (57.419 us; speedup 1.0000x reference)
//
#include <hip/hip_runtime.h>
#include <stdint.h>

#define NTOK 8192
#define NCOL 4096     // DIM == VOCAB
#define RANK 256
#define TPB  128      // tokens per block (4 waves x 32 tokens)
#define CPB  128      // cols per block (8 col-tiles) — r13: halved for backfill

typedef __attribute__((ext_vector_type(8))) short bf16x8;
typedef __attribute__((ext_vector_type(4))) float f32x4;

__device__ __forceinline__ unsigned short f2bf(float f) {
    unsigned int u = __float_as_uint(f);
    u += 0x7fffu + ((u >> 16) & 1u);   // RNE
    return (unsigned short)(u >> 16);
}

// ---- combined pre-pass ----
// blocks [0, 1024): A fp32 [4096][256] -> bf16 row-major (Abf, 2 MiB, L2-resident)
// blocks [1024, 1536): B fp32 [256][4096] -> bf16 MFMA-B-fragment order
//   frag layout: flat uint4 index = (ct*8 + ks)*64 + lane, 8 bf16 each:
//     element j = B[ks*32 + (lane>>4)*8 + j][ct*16 + (lane&15)]
__global__ __launch_bounds__(256) void prep_kernel(
    const float* __restrict__ A, const float* __restrict__ B,
    unsigned short* __restrict__ Abf, unsigned short* __restrict__ Bfrag)
{
    if (blockIdx.x < 1024) {
        int i = blockIdx.x * 256 + threadIdx.x;
        float4 v = reinterpret_cast<const float4*>(A)[i];
        ushort4 o;
        o.x = f2bf(v.x); o.y = f2bf(v.y); o.z = f2bf(v.z); o.w = f2bf(v.w);
        reinterpret_cast<ushort4*>(Abf)[i] = o;
    } else {
        int gt = (blockIdx.x - 1024) * 256 + threadIdx.x;
        int ct = gt >> 9;
        int rem = gt & 511;
        int ks = rem >> 6;
        int ln = rem & 63;
        int col = ct * 16 + (ln & 15);
        int kb  = ks * 32 + ((ln >> 4) << 3);
        unsigned short pk[8];
        #pragma unroll
        for (int j = 0; j < 8; ++j)
            pk[j] = f2bf(B[(size_t)(kb + j) * NCOL + col]);
        uint4 o;
        o.x = (unsigned)pk[0] | ((unsigned)pk[1] << 16);
        o.y = (unsigned)pk[2] | ((unsigned)pk[3] << 16);
        o.z = (unsigned)pk[4] | ((unsigned)pk[5] << 16);
        o.w = (unsigned)pk[6] | ((unsigned)pk[7] << 16);
        reinterpret_cast<uint4*>(Bfrag)[gt] = o;
    }
}

// ---- main: fused gather + LoRA GEMM + W add + mask ----
// r12 body (M=32 tok/wave, W-ring depth 4, B half-tile pipeline) with the
// block halved to 8 col-tiles: grid 2048 blocks = 2 cohorts/CU -> finished
// blocks get backfilled, converting block-runtime variance into overlap
// instead of CU idle time (r12 showed Occupancy 19% with a 1-cohort grid).
__global__ __launch_bounds__(256) void emb_lora_mfma(
    const int* __restrict__ x,
    const int* __restrict__ mask,
    const float* __restrict__ W,
    const unsigned short* __restrict__ Abf,
    const unsigned short* __restrict__ Bfrag,
    float* __restrict__ out)
{
    __shared__ int s_idx[TPB];
    __shared__ int s_msk[TPB];

    const int tid  = threadIdx.x;
    const int lane = tid & 63;
    const int wave = tid >> 6;        // wave owns tokens [wave*32, wave*32+32)
    const int tok0 = blockIdx.x * TPB;
    const int col0 = blockIdx.y * CPB;

    if (tid < TPB) {
        s_idx[tid] = x[tok0 + tid];
        s_msk[tid] = mask[tok0 + tid];
    }
    __syncthreads();

    // A fragments for both token groups (A-operand row = lane&15)
    const int a0row = s_idx[wave * 32 + (lane & 15)];
    const int a1row = s_idx[wave * 32 + 16 + (lane & 15)];
    const unsigned short* ap0 = Abf + (size_t)a0row * RANK + ((lane >> 4) << 3);
    const unsigned short* ap1 = Abf + (size_t)a1row * RANK + ((lane >> 4) << 3);
    bf16x8 aA[8], aB[8];
    #pragma unroll
    for (int s = 0; s < 8; ++s) {
        aA[s] = *reinterpret_cast<const bf16x8*>(ap0 + s * 32);
        aB[s] = *reinterpret_cast<const bf16x8*>(ap1 + s * 32);
    }

    // per-thread epilogue state: group g covers rows wave*32+g*16+(lane>>4)*4+r
    const int colb = col0 + (lane & 15);
    int msk0[4], msk1[4];
    unsigned woff0[4], woff1[4], ooff0[4], ooff1[4];
    #pragma unroll
    for (int r = 0; r < 4; ++r) {
        int row0 = wave * 32 + ((lane >> 4) << 2) + r;
        int row1 = row0 + 16;
        msk0[r] = s_msk[row0];
        msk1[r] = s_msk[row1];
        woff0[r] = (unsigned)s_idx[row0] * NCOL + colb;
        woff1[r] = (unsigned)s_idx[row1] * NCOL + colb;
        ooff0[r] = (unsigned)(tok0 + row0) * NCOL + colb;
        ooff1[r] = (unsigned)(tok0 + row1) * NCOL + colb;
    }

    // block's 8 col-tiles start at global col-tile blockIdx.y*8
    const uint4* bcol = reinterpret_cast<const uint4*>(Bfrag)
                        + (size_t)(blockIdx.y * 8) * 512 + lane;

    // W prefetch rings, depth 4 (r11 win), exec-masked loads
    // (explicit `if`, NOT ternary — r3: speculation doubled FETCH_SIZE)
    float wv0[4][4], wv1[4][4];
    #pragma unroll
    for (int p = 0; p < 4; ++p) {
        #pragma unroll
        for (int r = 0; r < 4; ++r) {
            float v0 = 0.0f, v1 = 0.0f;
            if (!msk0[r]) v0 = W[woff0[r] + p * 16];
            if (!msk1[r]) v1 = W[woff1[r] + p * 16];
            wv0[p][r] = v0;
            wv1[p][r] = v1;
        }
    }

    // B pipeline prologue: lo-half of tile 0
    uint4 bbL[4];
    #pragma unroll
    for (int s = 0; s < 4; ++s)
        bbL[s] = bcol[s * 64];

#define TILE_BODY(T, SLOT, PF)                                           \
    {                                                                    \
        const int t_ = (T);                                              \
        /* issue hi-half loads for this tile */                          \
        uint4 bbH[4];                                                    \
        _Pragma("unroll")                                                \
        for (int s = 0; s < 4; ++s)                                      \
            bbH[s] = bcol[t_ * 512 + (s + 4) * 64];                      \
        float wc0[4], wc1[4];                                            \
        _Pragma("unroll")                                                \
        for (int r = 0; r < 4; ++r) { wc0[r] = wv0[SLOT][r]; wc1[r] = wv1[SLOT][r]; } \
        if (PF) {                                                        \
            _Pragma("unroll")                                            \
            for (int r = 0; r < 4; ++r) {                                \
                float v0 = 0.0f, v1 = 0.0f;                              \
                if (!msk0[r]) v0 = W[woff0[r] + (t_ + 4) * 16];          \
                if (!msk1[r]) v1 = W[woff1[r] + (t_ + 4) * 16];          \
                wv0[SLOT][r] = v0;                                       \
                wv1[SLOT][r] = v1;                                       \
            }                                                            \
        }                                                                \
        /* MFMA on lo-half (bbL was loaded during the previous tile) */  \
        f32x4 acc00 = {0.f,0.f,0.f,0.f}, acc01 = {0.f,0.f,0.f,0.f};      \
        f32x4 acc10 = {0.f,0.f,0.f,0.f}, acc11 = {0.f,0.f,0.f,0.f};      \
        _Pragma("unroll")                                                \
        for (int s = 0; s < 4; ++s) {                                    \
            bf16x8 b0 = __builtin_bit_cast(bf16x8, bbL[s]);              \
            acc00 = __builtin_amdgcn_mfma_f32_16x16x32_bf16(aA[s], b0, acc00, 0, 0, 0); \
            acc10 = __builtin_amdgcn_mfma_f32_16x16x32_bf16(aB[s], b0, acc10, 0, 0, 0); \
        }                                                                \
        /* prefetch lo-half of the NEXT tile into bbL (tail: reload self) */ \
        {                                                                \
            const int tn_ = (t_ < 7) ? (t_ + 1) : t_;                    \
            _Pragma("unroll")                                            \
            for (int s = 0; s < 4; ++s)                                  \
                bbL[s] = bcol[tn_ * 512 + s * 64];                       \
        }                                                                \
        /* MFMA on hi-half (covered by MFMA-lo above) */                 \
        _Pragma("unroll")                                                \
        for (int s = 0; s < 4; ++s) {                                    \
            bf16x8 b1 = __builtin_bit_cast(bf16x8, bbH[s]);              \
            acc01 = __builtin_amdgcn_mfma_f32_16x16x32_bf16(aA[s + 4], b1, acc01, 0, 0, 0); \
            acc11 = __builtin_amdgcn_mfma_f32_16x16x32_bf16(aB[s + 4], b1, acc11, 0, 0, 0); \
        }                                                                \
        _Pragma("unroll")                                                \
        for (int r = 0; r < 4; ++r) {                                    \
            float v0 = msk0[r] ? 0.0f : (acc00[r] + acc01[r] + wc0[r]);  \
            float v1 = msk1[r] ? 0.0f : (acc10[r] + acc11[r] + wc1[r]);  \
            out[ooff0[r] + t_ * 16] = v0;                                \
            out[ooff1[r] + t_ * 16] = v1;                                \
        }                                                                \
    }

    // 8 tiles: first 4 with W prefetch (t+4), last 4 peeled (no prefetch)
    TILE_BODY(0, 0, 1);
    TILE_BODY(1, 1, 1);
    TILE_BODY(2, 2, 1);
    TILE_BODY(3, 3, 1);
    TILE_BODY(4, 0, 0);
    TILE_BODY(5, 1, 0);
    TILE_BODY(6, 2, 0);
    TILE_BODY(7, 3, 0);
#undef TILE_BODY
}

extern "C" void kernel_launch(void* const* d_in, const int* in_sizes, int n_in,
                              void* d_out, int out_size, void* d_ws, size_t ws_size,
                              hipStream_t stream) {
    (void)in_sizes; (void)n_in; (void)out_size; (void)ws_size;

    const int*   x    = (const int*)d_in[0];
    const int*   mask = (const int*)d_in[1];
    const float* W    = (const float*)d_in[2];
    const float* A    = (const float*)d_in[3];
    const float* B    = (const float*)d_in[4];
    float*       out  = (float*)d_out;

    unsigned short* Abf   = (unsigned short*)d_ws;                       // 2 MiB
    unsigned short* Bfrag = (unsigned short*)((char*)d_ws + (2u << 20)); // 2 MiB

    prep_kernel<<<dim3(1536), dim3(256), 0, stream>>>(A, B, Abf, Bfrag);

    dim3 grid(NTOK / TPB, NCOL / CPB);   // (64, 32) = 2048 blocks
    emb_lora_mfma<<<grid, dim3(256), 0, stream>>>(x, mask, W, Abf, Bfrag, out);
}

// Round 14
// 52.282 us; speedup vs baseline: 1.0982x; 1.0982x over previous
//
#include <hip/hip_runtime.h>
#include <stdint.h>

#define NTOK 8192
#define NCOL 4096     // DIM == VOCAB
#define RANK 256
#define TPB  128      // tokens per block (4 waves x 32 tokens)
#define CPB  256      // cols per block (16 col-tiles)

typedef __attribute__((ext_vector_type(8))) short bf16x8;
typedef __attribute__((ext_vector_type(4))) float f32x4;

__device__ __forceinline__ unsigned short f2bf(float f) {
    unsigned int u = __float_as_uint(f);
    u += 0x7fffu + ((u >> 16) & 1u);   // RNE
    return (unsigned short)(u >> 16);
}

// async global->LDS, 16B per lane; LDS dest = uniform base + lane*16 (m104)
__device__ __forceinline__ void gload_lds16(const uint4* g, uint4* l) {
    __builtin_amdgcn_global_load_lds(
        (const __attribute__((address_space(1))) void*)g,
        (__attribute__((address_space(3))) void*)l, 16, 0, 0);
}

// ---- combined pre-pass ----
// blocks [0, 1024): A fp32 [4096][256] -> bf16 row-major (Abf, 2 MiB, L2-resident)
// blocks [1024, 1536): B fp32 [256][4096] -> bf16 MFMA-B-fragment order
//   frag layout: flat uint4 index = (ct*8 + ks)*64 + lane, 8 bf16 each:
//     element j = B[ks*32 + (lane>>4)*8 + j][ct*16 + (lane&15)]
__global__ __launch_bounds__(256) void prep_kernel(
    const float* __restrict__ A, const float* __restrict__ B,
    unsigned short* __restrict__ Abf, unsigned short* __restrict__ Bfrag)
{
    if (blockIdx.x < 1024) {
        int i = blockIdx.x * 256 + threadIdx.x;
        float4 v = reinterpret_cast<const float4*>(A)[i];
        ushort4 o;
        o.x = f2bf(v.x); o.y = f2bf(v.y); o.z = f2bf(v.z); o.w = f2bf(v.w);
        reinterpret_cast<ushort4*>(Abf)[i] = o;
    } else {
        int gt = (blockIdx.x - 1024) * 256 + threadIdx.x;
        int ct = gt >> 9;
        int rem = gt & 511;
        int ks = rem >> 6;
        int ln = rem & 63;
        int col = ct * 16 + (ln & 15);
        int kb  = ks * 32 + ((ln >> 4) << 3);
        unsigned short pk[8];
        #pragma unroll
        for (int j = 0; j < 8; ++j)
            pk[j] = f2bf(B[(size_t)(kb + j) * NCOL + col]);
        uint4 o;
        o.x = (unsigned)pk[0] | ((unsigned)pk[1] << 16);
        o.y = (unsigned)pk[2] | ((unsigned)pk[3] << 16);
        o.z = (unsigned)pk[4] | ((unsigned)pk[5] << 16);
        o.w = (unsigned)pk[6] | ((unsigned)pk[7] << 16);
        reinterpret_cast<uint4*>(Bfrag)[gt] = o;
    }
}

// ---- main: fused gather + LoRA GEMM + W add + mask ----
// r12 economics (M=32 tok/wave, W-ring depth 4) with the B-path moved to
// LDS: each 8KB B-tile staged ONCE per block via async global_load_lds
// (double-buffered), consumed by all 4 waves via ds_read_b128. Removes the
// 4x per-wave B redundancy through L1 and the cross-tile B register state.
__global__ __launch_bounds__(256) void emb_lora_mfma(
    const int* __restrict__ x,
    const int* __restrict__ mask,
    const float* __restrict__ W,
    const unsigned short* __restrict__ Abf,
    const unsigned short* __restrict__ Bfrag,
    float* __restrict__ out)
{
    __shared__ int s_idx[TPB];
    __shared__ int s_msk[TPB];
    __shared__ uint4 b_lds[2][512];   // 2 x 8 KB (one B col-tile each)

    const int tid  = threadIdx.x;
    const int lane = tid & 63;
    const int wave = tid >> 6;        // wave owns tokens [wave*32, wave*32+32)
    const int tok0 = blockIdx.x * TPB;
    const int col0 = blockIdx.y * CPB;

    if (tid < TPB) {
        s_idx[tid] = x[tok0 + tid];
        s_msk[tid] = mask[tok0 + tid];
    }
    __syncthreads();

    // A fragments for both token groups (A-operand row = lane&15)
    const int a0row = s_idx[wave * 32 + (lane & 15)];
    const int a1row = s_idx[wave * 32 + 16 + (lane & 15)];
    const unsigned short* ap0 = Abf + (size_t)a0row * RANK + ((lane >> 4) << 3);
    const unsigned short* ap1 = Abf + (size_t)a1row * RANK + ((lane >> 4) << 3);
    bf16x8 aA[8], aB[8];
    #pragma unroll
    for (int s = 0; s < 8; ++s) {
        aA[s] = *reinterpret_cast<const bf16x8*>(ap0 + s * 32);
        aB[s] = *reinterpret_cast<const bf16x8*>(ap1 + s * 32);
    }

    // per-thread epilogue state: group g covers rows wave*32+g*16+(lane>>4)*4+r
    const int colb = col0 + (lane & 15);
    int msk0[4], msk1[4];
    unsigned woff0[4], woff1[4], ooff0[4], ooff1[4];
    #pragma unroll
    for (int r = 0; r < 4; ++r) {
        int row0 = wave * 32 + ((lane >> 4) << 2) + r;
        int row1 = row0 + 16;
        msk0[r] = s_msk[row0];
        msk1[r] = s_msk[row1];
        woff0[r] = (unsigned)s_idx[row0] * NCOL + colb;
        woff1[r] = (unsigned)s_idx[row1] * NCOL + colb;
        ooff0[r] = (unsigned)(tok0 + row0) * NCOL + colb;
        ooff1[r] = (unsigned)(tok0 + row1) * NCOL + colb;
    }

    // block's 16 col-tiles start at global col-tile blockIdx.y*16
    const uint4* bpanel = reinterpret_cast<const uint4*>(Bfrag)
                          + (size_t)(blockIdx.y * 16) * 512;

    // W prefetch rings, depth 4 (r11 win), exec-masked loads
    // (explicit `if`, NOT ternary — r3: speculation doubled FETCH_SIZE)
    float wv0[4][4], wv1[4][4];
    #pragma unroll
    for (int p = 0; p < 4; ++p) {
        #pragma unroll
        for (int r = 0; r < 4; ++r) {
            float v0 = 0.0f, v1 = 0.0f;
            if (!msk0[r]) v0 = W[woff0[r] + p * 16];
            if (!msk1[r]) v1 = W[woff1[r] + p * 16];
            wv0[p][r] = v0;
            wv1[p][r] = v1;
        }
    }

    // stage: wave stages its 2 KB of tile T into buffer BUF (async)
#define STAGE(T, BUF)                                                    \
    {                                                                    \
        const uint4* gs = bpanel + (T) * 512 + wave * 128 + lane;        \
        gload_lds16(gs,      &b_lds[BUF][wave * 128]);                   \
        gload_lds16(gs + 64, &b_lds[BUF][wave * 128 + 64]);              \
    }

    STAGE(0, 0);
    __syncthreads();   // drains vmcnt -> tile 0 staged

#define TILE_BODY(T, BUF, SLOT, PF)                                      \
    {                                                                    \
        const int t_ = (T);                                              \
        if (t_ < 15) { STAGE(t_ + 1, 1 - (BUF)); }                       \
        float wc0[4], wc1[4];                                            \
        _Pragma("unroll")                                                \
        for (int r = 0; r < 4; ++r) { wc0[r] = wv0[SLOT][r]; wc1[r] = wv1[SLOT][r]; } \
        if (PF) {                                                        \
            _Pragma("unroll")                                            \
            for (int r = 0; r < 4; ++r) {                                \
                float v0 = 0.0f, v1 = 0.0f;                              \
                if (!msk0[r]) v0 = W[woff0[r] + (t_ + 4) * 16];          \
                if (!msk1[r]) v1 = W[woff1[r] + (t_ + 4) * 16];          \
                wv0[SLOT][r] = v0;                                       \
                wv1[SLOT][r] = v1;                                       \
            }                                                            \
        }                                                                \
        uint4 bb[8];                                                     \
        _Pragma("unroll")                                                \
        for (int s = 0; s < 8; ++s)                                      \
            bb[s] = b_lds[BUF][s * 64 + lane];                           \
        f32x4 acc00 = {0.f,0.f,0.f,0.f}, acc01 = {0.f,0.f,0.f,0.f};      \
        f32x4 acc10 = {0.f,0.f,0.f,0.f}, acc11 = {0.f,0.f,0.f,0.f};      \
        _Pragma("unroll")                                                \
        for (int s = 0; s < 4; ++s) {                                    \
            bf16x8 b0 = __builtin_bit_cast(bf16x8, bb[s]);               \
            bf16x8 b1 = __builtin_bit_cast(bf16x8, bb[s + 4]);           \
            acc00 = __builtin_amdgcn_mfma_f32_16x16x32_bf16(aA[s],     b0, acc00, 0, 0, 0); \
            acc01 = __builtin_amdgcn_mfma_f32_16x16x32_bf16(aA[s + 4], b1, acc01, 0, 0, 0); \
            acc10 = __builtin_amdgcn_mfma_f32_16x16x32_bf16(aB[s],     b0, acc10, 0, 0, 0); \
            acc11 = __builtin_amdgcn_mfma_f32_16x16x32_bf16(aB[s + 4], b1, acc11, 0, 0, 0); \
        }                                                                \
        _Pragma("unroll")                                                \
        for (int r = 0; r < 4; ++r) {                                    \
            float v0 = msk0[r] ? 0.0f : (acc00[r] + acc01[r] + wc0[r]);  \
            float v1 = msk1[r] ? 0.0f : (acc10[r] + acc11[r] + wc1[r]);  \
            out[ooff0[r] + t_ * 16] = v0;                                \
            out[ooff1[r] + t_ * 16] = v1;                                \
        }                                                                \
        __syncthreads();  /* next tile staged; all waves done with BUF */ \
    }

    TILE_BODY(0,  0, 0, 1);
    TILE_BODY(1,  1, 1, 1);
    TILE_BODY(2,  0, 2, 1);
    TILE_BODY(3,  1, 3, 1);
    TILE_BODY(4,  0, 0, 1);
    TILE_BODY(5,  1, 1, 1);
    TILE_BODY(6,  0, 2, 1);
    TILE_BODY(7,  1, 3, 1);
    TILE_BODY(8,  0, 0, 1);
    TILE_BODY(9,  1, 1, 1);
    TILE_BODY(10, 0, 2, 1);
    TILE_BODY(11, 1, 3, 1);
    // peeled tail: no W prefetch (avoids OOB reads past the block's col range)
    TILE_BODY(12, 0, 0, 0);
    TILE_BODY(13, 1, 1, 0);
    TILE_BODY(14, 0, 2, 0);
    TILE_BODY(15, 1, 3, 0);
#undef TILE_BODY
#undef STAGE
}

extern "C" void kernel_launch(void* const* d_in, const int* in_sizes, int n_in,
                              void* d_out, int out_size, void* d_ws, size_t ws_size,
                              hipStream_t stream) {
    (void)in_sizes; (void)n_in; (void)out_size; (void)ws_size;

    const int*   x    = (const int*)d_in[0];
    const int*   mask = (const int*)d_in[1];
    const float* W    = (const float*)d_in[2];
    const float* A    = (const float*)d_in[3];
    const float* B    = (const float*)d_in[4];
    float*       out  = (float*)d_out;

    unsigned short* Abf   = (unsigned short*)d_ws;                       // 2 MiB
    unsigned short* Bfrag = (unsigned short*)((char*)d_ws + (2u << 20)); // 2 MiB

    prep_kernel<<<dim3(1536), dim3(256), 0, stream>>>(A, B, Abf, Bfrag);

    dim3 grid(NTOK / TPB, NCOL / CPB);   // (64, 16) = 1024 blocks
    emb_lora_mfma<<<grid, dim3(256), 0, stream>>>(x, mask, W, Abf, Bfrag, out);
}

// Round 15
// 49.419 us; speedup vs baseline: 1.1619x; 1.0579x over previous
//
#include <hip/hip_runtime.h>
#include <stdint.h>

#define NTOK 8192
#define NCOL 4096     // DIM == VOCAB
#define RANK 256
#define TPB  128      // tokens per block (4 waves x 32 tokens)
#define CPB  256      // cols per block (16 col-tiles)

typedef __attribute__((ext_vector_type(8))) short bf16x8;
typedef __attribute__((ext_vector_type(4))) float f32x4;

__device__ __forceinline__ unsigned short f2bf(float f) {
    unsigned int u = __float_as_uint(f);
    u += 0x7fffu + ((u >> 16) & 1u);   // RNE
    return (unsigned short)(u >> 16);
}

// async global->LDS, 16B per lane; LDS dest = uniform base + lane*16 (m104)
__device__ __forceinline__ void gload_lds16(const uint4* g, uint4* l) {
    __builtin_amdgcn_global_load_lds(
        (const __attribute__((address_space(1))) void*)g,
        (__attribute__((address_space(3))) void*)l, 16, 0, 0);
}

// ---- combined pre-pass ----
// blocks [0, 1024): A fp32 [4096][256] -> bf16 row-major (Abf, 2 MiB, L2-resident)
// blocks [1024, 1536): B fp32 [256][4096] -> bf16 MFMA-B-fragment order
//   frag layout: flat uint4 index = (ct*8 + ks)*64 + lane, 8 bf16 each:
//     element j = B[ks*32 + (lane>>4)*8 + j][ct*16 + (lane&15)]
__global__ __launch_bounds__(256) void prep_kernel(
    const float* __restrict__ A, const float* __restrict__ B,
    unsigned short* __restrict__ Abf, unsigned short* __restrict__ Bfrag)
{
    if (blockIdx.x < 1024) {
        int i = blockIdx.x * 256 + threadIdx.x;
        float4 v = reinterpret_cast<const float4*>(A)[i];
        ushort4 o;
        o.x = f2bf(v.x); o.y = f2bf(v.y); o.z = f2bf(v.z); o.w = f2bf(v.w);
        reinterpret_cast<ushort4*>(Abf)[i] = o;
    } else {
        int gt = (blockIdx.x - 1024) * 256 + threadIdx.x;
        int ct = gt >> 9;
        int rem = gt & 511;
        int ks = rem >> 6;
        int ln = rem & 63;
        int col = ct * 16 + (ln & 15);
        int kb  = ks * 32 + ((ln >> 4) << 3);
        unsigned short pk[8];
        #pragma unroll
        for (int j = 0; j < 8; ++j)
            pk[j] = f2bf(B[(size_t)(kb + j) * NCOL + col]);
        uint4 o;
        o.x = (unsigned)pk[0] | ((unsigned)pk[1] << 16);
        o.y = (unsigned)pk[2] | ((unsigned)pk[3] << 16);
        o.z = (unsigned)pk[4] | ((unsigned)pk[5] << 16);
        o.w = (unsigned)pk[6] | ((unsigned)pk[7] << 16);
        reinterpret_cast<uint4*>(Bfrag)[gt] = o;
    }
}

// ---- main: fused gather + LoRA GEMM + W add + mask ----
// r14 structure (LDS-staged B, W-ring depth 4) with the per-tile
// __syncthreads (full vmcnt(0) drain) replaced by counted-vmcnt + raw
// s_barrier (T4): per tile, issue [W-pref (masked)] [2 stage loads]
// sched_barrier(0) [8 stores] -> s_waitcnt vmcnt(8) covers the stage loads
// while the stores never block the barrier.
__global__ __launch_bounds__(256) void emb_lora_mfma(
    const int* __restrict__ x,
    const int* __restrict__ mask,
    const float* __restrict__ W,
    const unsigned short* __restrict__ Abf,
    const unsigned short* __restrict__ Bfrag,
    float* __restrict__ out)
{
    __shared__ int s_idx[TPB];
    __shared__ int s_msk[TPB];
    __shared__ uint4 b_lds[2][512];   // 2 x 8 KB (one B col-tile each)

    const int tid  = threadIdx.x;
    const int lane = tid & 63;
    const int wave = tid >> 6;        // wave owns tokens [wave*32, wave*32+32)
    const int tok0 = blockIdx.x * TPB;
    const int col0 = blockIdx.y * CPB;

    if (tid < TPB) {
        s_idx[tid] = x[tok0 + tid];
        s_msk[tid] = mask[tok0 + tid];
    }
    __syncthreads();

    // A fragments for both token groups (A-operand row = lane&15)
    const int a0row = s_idx[wave * 32 + (lane & 15)];
    const int a1row = s_idx[wave * 32 + 16 + (lane & 15)];
    const unsigned short* ap0 = Abf + (size_t)a0row * RANK + ((lane >> 4) << 3);
    const unsigned short* ap1 = Abf + (size_t)a1row * RANK + ((lane >> 4) << 3);
    bf16x8 aA[8], aB[8];
    #pragma unroll
    for (int s = 0; s < 8; ++s) {
        aA[s] = *reinterpret_cast<const bf16x8*>(ap0 + s * 32);
        aB[s] = *reinterpret_cast<const bf16x8*>(ap1 + s * 32);
    }

    // per-thread epilogue state: group g covers rows wave*32+g*16+(lane>>4)*4+r
    const int colb = col0 + (lane & 15);
    int msk0[4], msk1[4];
    unsigned woff0[4], woff1[4], ooff0[4], ooff1[4];
    #pragma unroll
    for (int r = 0; r < 4; ++r) {
        int row0 = wave * 32 + ((lane >> 4) << 2) + r;
        int row1 = row0 + 16;
        msk0[r] = s_msk[row0];
        msk1[r] = s_msk[row1];
        woff0[r] = (unsigned)s_idx[row0] * NCOL + colb;
        woff1[r] = (unsigned)s_idx[row1] * NCOL + colb;
        ooff0[r] = (unsigned)(tok0 + row0) * NCOL + colb;
        ooff1[r] = (unsigned)(tok0 + row1) * NCOL + colb;
    }

    // block's 16 col-tiles start at global col-tile blockIdx.y*16
    const uint4* bpanel = reinterpret_cast<const uint4*>(Bfrag)
                          + (size_t)(blockIdx.y * 16) * 512;

    // W prefetch rings, depth 4 (r11 win), exec-masked loads
    // (explicit `if`, NOT ternary — r3: speculation doubled FETCH_SIZE)
    float wv0[4][4], wv1[4][4];
    #pragma unroll
    for (int p = 0; p < 4; ++p) {
        #pragma unroll
        for (int r = 0; r < 4; ++r) {
            float v0 = 0.0f, v1 = 0.0f;
            if (!msk0[r]) v0 = W[woff0[r] + p * 16];
            if (!msk1[r]) v1 = W[woff1[r] + p * 16];
            wv0[p][r] = v0;
            wv1[p][r] = v1;
        }
    }

    // stage: wave stages its 2 KB of tile T into buffer BUF (async)
#define STAGE(T, BUF)                                                    \
    {                                                                    \
        const uint4* gs = bpanel + (T) * 512 + wave * 128 + lane;        \
        gload_lds16(gs,      &b_lds[BUF][wave * 128]);                   \
        gload_lds16(gs + 64, &b_lds[BUF][wave * 128 + 64]);              \
    }

    STAGE(0, 0);
    __syncthreads();   // one-time full drain: tile 0 staged, prologue done

#define TILE_BODY(T, BUF, SLOT, PF, LAST)                                \
    {                                                                    \
        const int t_ = (T);                                              \
        /* copy current W slot to regs BEFORE the slot is re-prefetched */ \
        float wc0[4], wc1[4];                                            \
        _Pragma("unroll")                                                \
        for (int r = 0; r < 4; ++r) { wc0[r] = wv0[SLOT][r]; wc1[r] = wv1[SLOT][r]; } \
        if (PF) {                                                        \
            _Pragma("unroll")                                            \
            for (int r = 0; r < 4; ++r) {                                \
                float v0 = 0.0f, v1 = 0.0f;                              \
                if (!msk0[r]) v0 = W[woff0[r] + (t_ + 4) * 16];          \
                if (!msk1[r]) v1 = W[woff1[r] + (t_ + 4) * 16];          \
                wv0[SLOT][r] = v0;                                       \
                wv1[SLOT][r] = v1;                                       \
            }                                                            \
        }                                                                \
        if (!(LAST)) { STAGE(t_ + 1, 1 - (BUF)); }                       \
        /* pin: all loads above issue before everything below */         \
        __builtin_amdgcn_sched_barrier(0);                               \
        uint4 bb[8];                                                     \
        _Pragma("unroll")                                                \
        for (int s = 0; s < 8; ++s)                                      \
            bb[s] = b_lds[BUF][s * 64 + lane];                           \
        f32x4 acc00 = {0.f,0.f,0.f,0.f}, acc01 = {0.f,0.f,0.f,0.f};      \
        f32x4 acc10 = {0.f,0.f,0.f,0.f}, acc11 = {0.f,0.f,0.f,0.f};      \
        _Pragma("unroll")                                                \
        for (int s = 0; s < 4; ++s) {                                    \
            bf16x8 b0 = __builtin_bit_cast(bf16x8, bb[s]);               \
            bf16x8 b1 = __builtin_bit_cast(bf16x8, bb[s + 4]);           \
            acc00 = __builtin_amdgcn_mfma_f32_16x16x32_bf16(aA[s],     b0, acc00, 0, 0, 0); \
            acc01 = __builtin_amdgcn_mfma_f32_16x16x32_bf16(aA[s + 4], b1, acc01, 0, 0, 0); \
            acc10 = __builtin_amdgcn_mfma_f32_16x16x32_bf16(aB[s],     b0, acc10, 0, 0, 0); \
            acc11 = __builtin_amdgcn_mfma_f32_16x16x32_bf16(aB[s + 4], b1, acc11, 0, 0, 0); \
        }                                                                \
        _Pragma("unroll")                                                \
        for (int r = 0; r < 4; ++r) {                                    \
            float v0 = msk0[r] ? 0.0f : (acc00[r] + acc01[r] + wc0[r]);  \
            float v1 = msk1[r] ? 0.0f : (acc10[r] + acc11[r] + wc1[r]);  \
            out[ooff0[r] + t_ * 16] = v0;                                \
            out[ooff1[r] + t_ * 16] = v1;                                \
        }                                                                \
        if (!(LAST)) {                                                   \
            /* counted wait: the 8 stores above are the ONLY ops allowed \
               outstanding -> stage loads (issued before them) are done; \
               stores never block the barrier (T4). */                   \
            asm volatile("s_waitcnt vmcnt(8)" ::: "memory");             \
            __builtin_amdgcn_s_barrier();                                \
        }                                                                \
    }

    TILE_BODY(0,  0, 0, 1, 0);
    TILE_BODY(1,  1, 1, 1, 0);
    TILE_BODY(2,  0, 2, 1, 0);
    TILE_BODY(3,  1, 3, 1, 0);
    TILE_BODY(4,  0, 0, 1, 0);
    TILE_BODY(5,  1, 1, 1, 0);
    TILE_BODY(6,  0, 2, 1, 0);
    TILE_BODY(7,  1, 3, 1, 0);
    TILE_BODY(8,  0, 0, 1, 0);
    TILE_BODY(9,  1, 1, 1, 0);
    TILE_BODY(10, 0, 2, 1, 0);
    TILE_BODY(11, 1, 3, 1, 0);
    // peeled tail: no W prefetch (avoids OOB reads past the block's col range)
    TILE_BODY(12, 0, 0, 0, 0);
    TILE_BODY(13, 1, 1, 0, 0);
    TILE_BODY(14, 0, 2, 0, 0);
    TILE_BODY(15, 1, 3, 0, 1);
#undef TILE_BODY
#undef STAGE
}

extern "C" void kernel_launch(void* const* d_in, const int* in_sizes, int n_in,
                              void* d_out, int out_size, void* d_ws, size_t ws_size,
                              hipStream_t stream) {
    (void)in_sizes; (void)n_in; (void)out_size; (void)ws_size;

    const int*   x    = (const int*)d_in[0];
    const int*   mask = (const int*)d_in[1];
    const float* W    = (const float*)d_in[2];
    const float* A    = (const float*)d_in[3];
    const float* B    = (const float*)d_in[4];
    float*       out  = (float*)d_out;

    unsigned short* Abf   = (unsigned short*)d_ws;                       // 2 MiB
    unsigned short* Bfrag = (unsigned short*)((char*)d_ws + (2u << 20)); // 2 MiB

    prep_kernel<<<dim3(1536), dim3(256), 0, stream>>>(A, B, Abf, Bfrag);

    dim3 grid(NTOK / TPB, NCOL / CPB);   // (64, 16) = 1024 blocks
    emb_lora_mfma<<<grid, dim3(256), 0, stream>>>(x, mask, W, Abf, Bfrag, out);
}